// Round 1
// baseline (590.052 us; speedup 1.0000x reference)
//
#include <hip/hip_runtime.h>
#include <math.h>

#define BB 32
#define SS 2048
#define DD 512
#define AD 512
#define KD 16          // d-chunk staged in LDS
#define RROWS 64       // rows (b,s) per block

// ---------------- K0: probe mask dtype ----------------
// If mask is int32 {0,1}, every byte at index i%4!=0 is 0.
// If mask is 1-byte bool, ~half of those bytes are 1.  Reads only first 64KB
// (safe under both layouts).
__global__ void mask_probe_kernel(const unsigned char* __restrict__ m8,
                                  int* __restrict__ flag) {
    int t = threadIdx.x + blockIdx.x * 256;
    int any = 0;
    for (int i = t; i < BB * SS; i += gridDim.x * 256) {
        if ((i & 3) && m8[i]) any = 1;
    }
    if (__any(any)) {
        if ((threadIdx.x & 63) == 0) atomicOr(flag, 1);
    }
}

// ---------------- K1: w1q[b][a] = dot(query[b,:], W1[a,:]) ----------------
// grid (AD/4, B), 256 thr = 4 waves, one wave per a.
__global__ void w1q_kernel(const float* __restrict__ query,
                           const float* __restrict__ W1,
                           float* __restrict__ w1q) {
    int b = blockIdx.y;
    int a = blockIdx.x * 4 + (threadIdx.x >> 6);
    int lane = threadIdx.x & 63;
    const float4* q4 = (const float4*)(query + (size_t)b * DD) + lane * 2;
    const float4* w4 = (const float4*)(W1 + (size_t)a * DD) + lane * 2;
    float4 qa = q4[0], qb = q4[1];
    float4 wa = w4[0], wb = w4[1];
    float acc = qa.x * wa.x + qa.y * wa.y + qa.z * wa.z + qa.w * wa.w
              + qb.x * wb.x + qb.y * wb.y + qb.z * wb.z + qb.w * wb.w;
#pragma unroll
    for (int off = 32; off > 0; off >>= 1) acc += __shfl_down(acc, off);
    if (lane == 0) w1q[(size_t)b * AD + a] = acc;
}

// ---------------- K2: scores[b][s] = sum_a tanh(w1q[b][a]+dot(keys[b,s,:],W2[a,:]))*v[a]
// block: 256 thr; rows = 64 (one b), full a-width 512.
// thread (tr = t&63, tc = t>>6): 16 rows (tc*16..+15) x 8 a (tr*4..+3, 256+tr*4..+3)
__global__ __launch_bounds__(256)
void scores_kernel(const float* __restrict__ keys,
                   const float* __restrict__ W2,
                   const float* __restrict__ w1q,
                   const float* __restrict__ v,
                   float* __restrict__ scores) {
    __shared__ float k_lds[KD][RROWS + 4];   // [d][row], stride 68: 2-way max on transposed writes
    __shared__ float w_lds[KD][AD + 4];      // [d][a],  stride 516

    const int t  = threadIdx.x;
    const int tr = t & 63;
    const int tc = t >> 6;                   // wave id 0..3
    const int b  = blockIdx.y;
    const int s0 = blockIdx.x * RROWS;

    const float* keys_blk = keys + ((size_t)b * SS + s0) * DD;

    // preload w1q, v for this thread's 8 a-values
    float w1qv[8], vv[8];
    {
        const float4* w1q4 = (const float4*)(w1q + (size_t)b * AD);
        const float4* v4   = (const float4*)v;
        float4 x0 = w1q4[tr], x1 = w1q4[tr + 64];
        float4 y0 = v4[tr],   y1 = v4[tr + 64];
        w1qv[0]=x0.x; w1qv[1]=x0.y; w1qv[2]=x0.z; w1qv[3]=x0.w;
        w1qv[4]=x1.x; w1qv[5]=x1.y; w1qv[6]=x1.z; w1qv[7]=x1.w;
        vv[0]=y0.x; vv[1]=y0.y; vv[2]=y0.z; vv[3]=y0.w;
        vv[4]=y1.x; vv[5]=y1.y; vv[6]=y1.z; vv[7]=y1.w;
    }

    float acc[16][8];
#pragma unroll
    for (int r = 0; r < 16; ++r)
#pragma unroll
        for (int j = 0; j < 8; ++j) acc[r][j] = 0.f;

    const int kr = t >> 2, kdq = t & 3;      // keys staging: row kr, float4 kdq

    for (int d0 = 0; d0 < DD; d0 += KD) {
        // global loads for this chunk (to regs)
        float4 kv = *(const float4*)(keys_blk + (size_t)kr * DD + d0 + kdq * 4);
        float4 wv[8];
#pragma unroll
        for (int i = 0; i < 8; ++i) {
            int idx = t + 256 * i;
            int a = idx >> 2, dq = idx & 3;
            wv[i] = *(const float4*)(W2 + (size_t)a * DD + d0 + dq * 4);
        }
        __syncthreads();                     // previous iter done reading LDS
        // transposed stores: [d][row] / [d][a]
        k_lds[kdq*4+0][kr] = kv.x; k_lds[kdq*4+1][kr] = kv.y;
        k_lds[kdq*4+2][kr] = kv.z; k_lds[kdq*4+3][kr] = kv.w;
#pragma unroll
        for (int i = 0; i < 8; ++i) {
            int idx = t + 256 * i;
            int a = idx >> 2, dq = idx & 3;
            w_lds[dq*4+0][a] = wv[i].x; w_lds[dq*4+1][a] = wv[i].y;
            w_lds[dq*4+2][a] = wv[i].z; w_lds[dq*4+3][a] = wv[i].w;
        }
        __syncthreads();

#pragma unroll 4
        for (int dl = 0; dl < KD; ++dl) {
            // keys: wave-uniform addresses (broadcast reads)
            const float4 k0 = *(const float4*)&k_lds[dl][tc*16 + 0];
            const float4 k1 = *(const float4*)&k_lds[dl][tc*16 + 4];
            const float4 k2 = *(const float4*)&k_lds[dl][tc*16 + 8];
            const float4 k3 = *(const float4*)&k_lds[dl][tc*16 + 12];
            const float4 wA = *(const float4*)&w_lds[dl][tr*4];
            const float4 wB = *(const float4*)&w_lds[dl][tr*4 + 256];
            float kk[16] = {k0.x,k0.y,k0.z,k0.w, k1.x,k1.y,k1.z,k1.w,
                            k2.x,k2.y,k2.z,k2.w, k3.x,k3.y,k3.z,k3.w};
            float ww[8]  = {wA.x,wA.y,wA.z,wA.w, wB.x,wB.y,wB.z,wB.w};
#pragma unroll
            for (int r = 0; r < 16; ++r)
#pragma unroll
                for (int j = 0; j < 8; ++j)
                    acc[r][j] = fmaf(kk[r], ww[j], acc[r][j]);
        }
    }

    // epilogue: tanh + v-weighted sum over a (8 local + 64 lanes = 512)
#pragma unroll
    for (int r = 0; r < 16; ++r) {
        float sacc = 0.f;
#pragma unroll
        for (int j = 0; j < 8; ++j)
            sacc += tanhf(acc[r][j] + w1qv[j]) * vv[j];
#pragma unroll
        for (int off = 32; off > 0; off >>= 1) sacc += __shfl_down(sacc, off);
        if (tr == 0) scores[(size_t)b * SS + s0 + tc * 16 + r] = sacc;
    }
}

// ---------------- K3: masked softmax over s ----------------
__global__ void softmax_kernel(const float* __restrict__ scores,
                               const int* __restrict__ mask_i32,
                               const unsigned char* __restrict__ mask_u8,
                               const int* __restrict__ flag,
                               float* __restrict__ out) {
    const int b = blockIdx.x;
    const int t = threadIdx.x;
    __shared__ float rmax[4], rsum[4];
    const int wid = t >> 6, lane = t & 63;

    float sv[8]; int mv[8];
    const int bytes = (*flag != 0);
    if (bytes) {
#pragma unroll
        for (int k = 0; k < 8; ++k) {
            int i = t + 256 * k;
            sv[k] = scores[(size_t)b * SS + i];
            mv[k] = (int)mask_u8[(size_t)b * SS + i];
        }
    } else {
#pragma unroll
        for (int k = 0; k < 8; ++k) {
            int i = t + 256 * k;
            sv[k] = scores[(size_t)b * SS + i];
            mv[k] = mask_i32[(size_t)b * SS + i];
        }
    }

    float mx = -INFINITY;
#pragma unroll
    for (int k = 0; k < 8; ++k) mx = fmaxf(mx, mv[k] ? sv[k] : -INFINITY);
#pragma unroll
    for (int off = 32; off > 0; off >>= 1) mx = fmaxf(mx, __shfl_xor(mx, off));
    if (lane == 0) rmax[wid] = mx;
    __syncthreads();
    mx = fmaxf(fmaxf(rmax[0], rmax[1]), fmaxf(rmax[2], rmax[3]));

    float ev[8]; float sum = 0.f;
#pragma unroll
    for (int k = 0; k < 8; ++k) {
        ev[k] = mv[k] ? expf(sv[k] - mx) : 0.f;
        sum += ev[k];
    }
#pragma unroll
    for (int off = 32; off > 0; off >>= 1) sum += __shfl_xor(sum, off);
    if (lane == 0) rsum[wid] = sum;
    __syncthreads();
    sum = rsum[0] + rsum[1] + rsum[2] + rsum[3];
    float inv = 1.f / sum;
#pragma unroll
    for (int k = 0; k < 8; ++k)
        out[(size_t)b * SS + t + 256 * k] = ev[k] * inv;
}

extern "C" void kernel_launch(void* const* d_in, const int* in_sizes, int n_in,
                              void* d_out, int out_size, void* d_ws, size_t ws_size,
                              hipStream_t stream) {
    const float* query = (const float*)d_in[0];
    const float* keys  = (const float*)d_in[1];
    const void*  mask  = d_in[2];
    const float* W1    = (const float*)d_in[3];
    const float* W2    = (const float*)d_in[4];
    const float* v     = (const float*)d_in[5];
    float* out = (float*)d_out;

    float* ws     = (float*)d_ws;
    int*   flag   = (int*)d_ws;
    float* w1q    = ws + 64;
    float* scores = ws + 64 + BB * AD;

    hipMemsetAsync(flag, 0, 4, stream);
    mask_probe_kernel<<<64, 256, 0, stream>>>((const unsigned char*)mask, flag);
    w1q_kernel<<<dim3(AD / 4, BB), 256, 0, stream>>>(query, W1, w1q);
    scores_kernel<<<dim3(SS / RROWS, BB), 256, 0, stream>>>(keys, W2, w1q, v, scores);
    softmax_kernel<<<BB, 256, 0, stream>>>(scores, (const int*)mask,
                                           (const unsigned char*)mask, flag, out);
}

// Round 2
// 316.925 us; speedup vs baseline: 1.8618x; 1.8618x over previous
//
#include <hip/hip_runtime.h>
#include <math.h>

#define BB 32
#define SS 2048
#define DD 512
#define AD 512

#define BM 128
#define BN 128
#define BK 32
#define LDK (BK + 8)   // 40 elems = 80 B row stride: frag reads 2-way max (free)

typedef __bf16 bf16;
typedef __attribute__((ext_vector_type(8))) __bf16 bf16x8;
typedef __attribute__((ext_vector_type(4))) __bf16 bf16x4;
typedef __attribute__((ext_vector_type(4))) float floatx4;

// ---------------- K0: probe mask dtype ----------------
__global__ void mask_probe_kernel(const unsigned char* __restrict__ m8,
                                  int* __restrict__ flag) {
    int t = threadIdx.x + blockIdx.x * 256;
    int any = 0;
    for (int i = t; i < BB * SS; i += gridDim.x * 256) {
        if ((i & 3) && m8[i]) any = 1;
    }
    if (__any(any)) {
        if ((threadIdx.x & 63) == 0) atomicOr(flag, 1);
    }
}

// ---------------- K1: w1q[b][a] = dot(query[b,:], W1[a,:]) ----------------
__global__ void w1q_kernel(const float* __restrict__ query,
                           const float* __restrict__ W1,
                           float* __restrict__ w1q) {
    int b = blockIdx.y;
    int a = blockIdx.x * 4 + (threadIdx.x >> 6);
    int lane = threadIdx.x & 63;
    const float4* q4 = (const float4*)(query + (size_t)b * DD) + lane * 2;
    const float4* w4 = (const float4*)(W1 + (size_t)a * DD) + lane * 2;
    float4 qa = q4[0], qb = q4[1];
    float4 wa = w4[0], wb = w4[1];
    float acc = qa.x * wa.x + qa.y * wa.y + qa.z * wa.z + qa.w * wa.w
              + qb.x * wb.x + qb.y * wb.y + qb.z * wb.z + qb.w * wb.w;
#pragma unroll
    for (int off = 32; off > 0; off >>= 1) acc += __shfl_down(acc, off);
    if (lane == 0) w1q[(size_t)b * AD + a] = acc;
}

// ---------------- K2: MFMA GEMM + fused tanh/v epilogue ----------------
// C[s,a] = sum_d keys[b,s,d]*W2[a,d]; partial[b,s,tile] = sum_{a in tile}
// tanh(C + w1q[b,a]) * v[a].  grid (SS/BM, AD/BN, BB), 256 thr = 4 waves,
// wave sub-tile 64x64 (4x4 of 16x16x32 MFMA).
__global__ __launch_bounds__(256, 2)
void gemm_scores_kernel(const float* __restrict__ keys,
                        const float* __restrict__ W2,
                        const float* __restrict__ w1q,
                        const float* __restrict__ v,
                        float* __restrict__ partial) {
    __shared__ bf16 a_lds[BM][LDK];
    __shared__ bf16 b_lds[BN][LDK];
    __shared__ float s_red[BM];

    const int t    = threadIdx.x;
    const int lane = t & 63;
    const int w    = t >> 6;
    const int ml   = lane & 15;       // n-col (B) / m-row (A) within 16-tile
    const int kg   = lane >> 4;       // k-group (quad)
    const int b    = blockIdx.z;
    const int s0   = blockIdx.x * BM;
    const int a0   = blockIdx.y * BN;
    const int m_off = (w & 1) * 64;
    const int n_off = (w >> 1) * 64;

    const float* Ablk = keys + ((size_t)b * SS + s0) * DD;
    const float* Bblk = W2 + (size_t)a0 * DD;

    if (t < BM) s_red[t] = 0.f;

    floatx4 acc[4][4];
#pragma unroll
    for (int mi = 0; mi < 4; ++mi)
#pragma unroll
        for (int ni = 0; ni < 4; ++ni)
            acc[mi][ni] = (floatx4)(0.f);

    // staging addressing: idx = t + 256*i; row = idx>>3 (8 float4 per row of 32)
    float4 ga[4], gb[4];
#pragma unroll
    for (int i = 0; i < 4; ++i) {
        int idx = t + 256 * i;
        int r = idx >> 3, c = idx & 7;
        ga[i] = *(const float4*)(Ablk + (size_t)r * DD + c * 4);
        gb[i] = *(const float4*)(Bblk + (size_t)r * DD + c * 4);
    }

    for (int chunk = 0; chunk < DD / BK; ++chunk) {
        __syncthreads();   // previous iter done reading LDS
#pragma unroll
        for (int i = 0; i < 4; ++i) {
            int idx = t + 256 * i;
            int r = idx >> 3, c = idx & 7;
            bf16x4 pa, pb;
            pa[0] = (bf16)ga[i].x; pa[1] = (bf16)ga[i].y;
            pa[2] = (bf16)ga[i].z; pa[3] = (bf16)ga[i].w;
            pb[0] = (bf16)gb[i].x; pb[1] = (bf16)gb[i].y;
            pb[2] = (bf16)gb[i].z; pb[3] = (bf16)gb[i].w;
            *(bf16x4*)&a_lds[r][c * 4] = pa;
            *(bf16x4*)&b_lds[r][c * 4] = pb;
        }
        __syncthreads();

        if (chunk < DD / BK - 1) {
            int d0 = (chunk + 1) * BK;
#pragma unroll
            for (int i = 0; i < 4; ++i) {
                int idx = t + 256 * i;
                int r = idx >> 3, c = idx & 7;
                ga[i] = *(const float4*)(Ablk + (size_t)r * DD + d0 + c * 4);
                gb[i] = *(const float4*)(Bblk + (size_t)r * DD + d0 + c * 4);
            }
        }

        bf16x8 af[4], bfr[4];
#pragma unroll
        for (int mi = 0; mi < 4; ++mi)
            af[mi] = *(const bf16x8*)&a_lds[m_off + mi * 16 + ml][kg * 8];
#pragma unroll
        for (int ni = 0; ni < 4; ++ni)
            bfr[ni] = *(const bf16x8*)&b_lds[n_off + ni * 16 + ml][kg * 8];
#pragma unroll
        for (int mi = 0; mi < 4; ++mi)
#pragma unroll
            for (int ni = 0; ni < 4; ++ni)
                acc[mi][ni] = __builtin_amdgcn_mfma_f32_16x16x32_bf16(
                    af[mi], bfr[ni], acc[mi][ni], 0, 0, 0);
    }

    // epilogue: tanh + v-weight, reduce over this block's 128 a's per s
    float w1qa[4], va[4];
#pragma unroll
    for (int ni = 0; ni < 4; ++ni) {
        int a = a0 + n_off + ni * 16 + ml;
        w1qa[ni] = w1q[(size_t)b * AD + a];
        va[ni]   = v[a];
    }
#pragma unroll
    for (int mi = 0; mi < 4; ++mi) {
#pragma unroll
        for (int reg = 0; reg < 4; ++reg) {
            float p = 0.f;
#pragma unroll
            for (int ni = 0; ni < 4; ++ni) {
                float x = acc[mi][ni][reg] + w1qa[ni];
                float th = 1.f - 2.f / (1.f + __expf(2.f * x));
                p = fmaf(th, va[ni], p);
            }
            // sum over the 16 lanes of this quad (16 n-cols)
            p += __shfl_xor(p, 1);
            p += __shfl_xor(p, 2);
            p += __shfl_xor(p, 4);
            p += __shfl_xor(p, 8);
            if (ml == 0)
                atomicAdd(&s_red[m_off + mi * 16 + kg * 4 + reg], p);
        }
    }
    __syncthreads();
    if (t < BM)
        partial[(((size_t)b * SS) + s0 + t) * 4 + blockIdx.y] = s_red[t];
}

// ---------------- K3: combine partials + masked softmax over s ----------------
__global__ void softmax_kernel(const float* __restrict__ partial,
                               const int* __restrict__ mask_i32,
                               const unsigned char* __restrict__ mask_u8,
                               const int* __restrict__ flag,
                               float* __restrict__ out) {
    const int b = blockIdx.x;
    const int t = threadIdx.x;
    __shared__ float rmax[4], rsum[4];
    const int wid = t >> 6, lane = t & 63;

    float sv[8]; int mv[8];
    const int bytes = (*flag != 0);
#pragma unroll
    for (int k = 0; k < 8; ++k) {
        int i = t + 256 * k;
        float4 p4 = *(const float4*)(partial + ((size_t)b * SS + i) * 4);
        sv[k] = (p4.x + p4.y) + (p4.z + p4.w);
        mv[k] = bytes ? (int)mask_u8[(size_t)b * SS + i]
                      : mask_i32[(size_t)b * SS + i];
    }

    float mx = -INFINITY;
#pragma unroll
    for (int k = 0; k < 8; ++k) mx = fmaxf(mx, mv[k] ? sv[k] : -INFINITY);
#pragma unroll
    for (int off = 32; off > 0; off >>= 1) mx = fmaxf(mx, __shfl_xor(mx, off));
    if (lane == 0) rmax[wid] = mx;
    __syncthreads();
    mx = fmaxf(fmaxf(rmax[0], rmax[1]), fmaxf(rmax[2], rmax[3]));

    float ev[8]; float sum = 0.f;
#pragma unroll
    for (int k = 0; k < 8; ++k) {
        ev[k] = mv[k] ? __expf(sv[k] - mx) : 0.f;
        sum += ev[k];
    }
#pragma unroll
    for (int off = 32; off > 0; off >>= 1) sum += __shfl_xor(sum, off);
    if (lane == 0) rsum[wid] = sum;
    __syncthreads();
    sum = (rsum[0] + rsum[1]) + (rsum[2] + rsum[3]);
    float inv = 1.f / sum;
#pragma unroll
    for (int k = 0; k < 8; ++k)
        out[(size_t)b * SS + t + 256 * k] = ev[k] * inv;
}

extern "C" void kernel_launch(void* const* d_in, const int* in_sizes, int n_in,
                              void* d_out, int out_size, void* d_ws, size_t ws_size,
                              hipStream_t stream) {
    const float* query = (const float*)d_in[0];
    const float* keys  = (const float*)d_in[1];
    const void*  mask  = d_in[2];
    const float* W1    = (const float*)d_in[3];
    const float* W2    = (const float*)d_in[4];
    const float* v     = (const float*)d_in[5];
    float* out = (float*)d_out;

    float* ws      = (float*)d_ws;
    int*   flag    = (int*)d_ws;
    float* w1q     = ws + 64;                       // 32*512
    float* partial = ws + 64 + BB * AD;             // 32*2048*4 floats (1 MB)

    hipMemsetAsync(flag, 0, 4, stream);
    mask_probe_kernel<<<64, 256, 0, stream>>>((const unsigned char*)mask, flag);
    w1q_kernel<<<dim3(AD / 4, BB), 256, 0, stream>>>(query, W1, w1q);
    gemm_scores_kernel<<<dim3(SS / BM, AD / BN, BB), 256, 0, stream>>>(
        keys, W2, w1q, v, partial);
    softmax_kernel<<<BB, 256, 0, stream>>>(partial, (const int*)mask,
                                           (const unsigned char*)mask, flag, out);
}

// Round 3
// 266.863 us; speedup vs baseline: 2.2111x; 1.1876x over previous
//
#include <hip/hip_runtime.h>
#include <math.h>

#define BB 32
#define SS 2048
#define DD 512
#define AD 512

#define BM 128
#define BN 128
#define BK 64    // bf16 elems per K-chunk; row = 128 B = 8 x 16B chunks

typedef __bf16 bf16;
typedef __attribute__((ext_vector_type(8))) __bf16 bf16x8;
typedef __attribute__((ext_vector_type(4))) __bf16 bf16x4;
typedef __attribute__((ext_vector_type(4))) float floatx4;

__device__ inline void async16(const void* g, void* l) {
    __builtin_amdgcn_global_load_lds(
        (const __attribute__((address_space(1))) unsigned int*)g,
        (__attribute__((address_space(3))) unsigned int*)l, 16, 0, 0);
}

// ---------------- K0: probe mask dtype ----------------
__global__ void mask_probe_kernel(const unsigned char* __restrict__ m8,
                                  int* __restrict__ flag) {
    int t = threadIdx.x + blockIdx.x * 256;
    int any = 0;
    for (int i = t; i < BB * SS; i += gridDim.x * 256) {
        if ((i & 3) && m8[i]) any = 1;
    }
    if (__any(any)) {
        if ((threadIdx.x & 63) == 0) atomicOr(flag, 1);
    }
}

// ---------------- K0b: fp32 -> bf16 convert (memory-bound) ----------------
__global__ void convert_kernel(const float* __restrict__ src,
                               bf16* __restrict__ dst, int n8) {
    int i = threadIdx.x + blockIdx.x * 256;
    if (i >= n8) return;
    const float4* s4 = (const float4*)src + (size_t)i * 2;
    float4 x = s4[0], y = s4[1];
    bf16x8 o;
    o[0] = (bf16)x.x; o[1] = (bf16)x.y; o[2] = (bf16)x.z; o[3] = (bf16)x.w;
    o[4] = (bf16)y.x; o[5] = (bf16)y.y; o[6] = (bf16)y.z; o[7] = (bf16)y.w;
    *(bf16x8*)(dst + (size_t)i * 8) = o;
}

// ---------------- K1: w1q[b][a] = dot(query[b,:], W1[a,:]) (fp32) ----------
__global__ void w1q_kernel(const float* __restrict__ query,
                           const float* __restrict__ W1,
                           float* __restrict__ w1q) {
    int b = blockIdx.y;
    int a = blockIdx.x * 4 + (threadIdx.x >> 6);
    int lane = threadIdx.x & 63;
    const float4* q4 = (const float4*)(query + (size_t)b * DD) + lane * 2;
    const float4* w4 = (const float4*)(W1 + (size_t)a * DD) + lane * 2;
    float4 qa = q4[0], qb = q4[1];
    float4 wa = w4[0], wb = w4[1];
    float acc = qa.x * wa.x + qa.y * wa.y + qa.z * wa.z + qa.w * wa.w
              + qb.x * wb.x + qb.y * wb.y + qb.z * wb.z + qb.w * wb.w;
#pragma unroll
    for (int off = 32; off > 0; off >>= 1) acc += __shfl_down(acc, off);
    if (lane == 0) w1q[(size_t)b * AD + a] = acc;
}

// ---------------- K2: m97-style MFMA GEMM + fused tanh/v epilogue ---------
// A = keys_bf16 [BB*SS x DD] row-major, B = W2_bf16 [AD x DD] row-major.
// grid (SS/BM, AD/BN, BB), 256 thr = 4 waves, wave = 64x64 (4x4 16x16x32).
// LDS layout XOR-swizzled at 16B granularity: data of k-chunk c for row r is
// stored at chunk position c ^ (r&7). Staging applies the swizzle on the
// per-lane GLOBAL address (LDS dest must stay wave-uniform-base + lane*16);
// frag reads invert it -> both sides conflict-free, no padding needed.
__global__ __launch_bounds__(256, 4)
void gemm_scores_mfma(const bf16* __restrict__ keysb,
                      const bf16* __restrict__ W2b,
                      const float* __restrict__ w1q,
                      const float* __restrict__ v,
                      float* __restrict__ partial, int tiles_y) {
    __shared__ bf16 a_lds[BM * BK];
    __shared__ bf16 b_lds[BN * BK];
    __shared__ float s_red[BM];

    const int t    = threadIdx.x;
    const int lane = t & 63;
    const int w    = t >> 6;
    const int ml   = lane & 15;
    const int kg   = lane >> 4;
    const int b    = blockIdx.z;
    const int s0   = blockIdx.x * BM;
    const int a0   = blockIdx.y * BN;
    const int m_off = (w & 1) * 64;
    const int n_off = (w >> 1) * 64;

    const bf16* Ablk = keysb + ((size_t)b * SS + s0) * DD;
    const bf16* Bblk = W2b + (size_t)a0 * DD;

    if (t < BM) s_red[t] = 0.f;

    floatx4 acc[4][4];
#pragma unroll
    for (int mi = 0; mi < 4; ++mi)
#pragma unroll
        for (int ni = 0; ni < 4; ++ni)
            acc[mi][ni] = (floatx4)(0.f);

    const int rr = lane >> 3;   // row-within-8 for staging
    const int cc = lane & 7;    // 16B chunk index for staging

    for (int chunk = 0; chunk < DD / BK; ++chunk) {
        const int d0 = chunk * BK;
        // async global->LDS, swizzled source chunk
#pragma unroll
        for (int i = 0; i < 4; ++i) {
            int r  = w * 32 + i * 8 + rr;
            int cs = cc ^ (r & 7);
            const bf16* ga = Ablk + (size_t)r * DD + d0 + cs * 8;
            const bf16* gb = Bblk + (size_t)r * DD + d0 + cs * 8;
            async16(ga, &a_lds[(w * 32 + i * 8) * BK]);
            async16(gb, &b_lds[(w * 32 + i * 8) * BK]);
        }
        __syncthreads();   // drains vmcnt -> tiles staged

#pragma unroll
        for (int ks = 0; ks < 2; ++ks) {
            bf16x8 af[4], bfr[4];
#pragma unroll
            for (int mi = 0; mi < 4; ++mi) {
                int R = m_off + mi * 16 + ml;
                int c = (ks * 4 + kg) ^ (R & 7);
                af[mi] = *(const bf16x8*)&a_lds[R * BK + c * 8];
            }
#pragma unroll
            for (int ni = 0; ni < 4; ++ni) {
                int R = n_off + ni * 16 + ml;
                int c = (ks * 4 + kg) ^ (R & 7);
                bfr[ni] = *(const bf16x8*)&b_lds[R * BK + c * 8];
            }
#pragma unroll
            for (int mi = 0; mi < 4; ++mi)
#pragma unroll
                for (int ni = 0; ni < 4; ++ni)
                    acc[mi][ni] = __builtin_amdgcn_mfma_f32_16x16x32_bf16(
                        af[mi], bfr[ni], acc[mi][ni], 0, 0, 0);
        }
        __syncthreads();   // done reading before next stage overwrites
    }

    // epilogue: tanh + v-weight, reduce over this block's 128 a's per s
    float w1qa[4], va[4];
#pragma unroll
    for (int ni = 0; ni < 4; ++ni) {
        int a = a0 + n_off + ni * 16 + ml;
        w1qa[ni] = w1q[(size_t)b * AD + a];
        va[ni]   = v[a];
    }
#pragma unroll
    for (int mi = 0; mi < 4; ++mi) {
#pragma unroll
        for (int reg = 0; reg < 4; ++reg) {
            float p = 0.f;
#pragma unroll
            for (int ni = 0; ni < 4; ++ni) {
                float x = acc[mi][ni][reg] + w1qa[ni];
                float th = 1.f - 2.f / (1.f + __expf(2.f * x));
                p = fmaf(th, va[ni], p);
            }
            p += __shfl_xor(p, 1);
            p += __shfl_xor(p, 2);
            p += __shfl_xor(p, 4);
            p += __shfl_xor(p, 8);
            if (ml == 0)
                atomicAdd(&s_red[m_off + mi * 16 + kg * 4 + reg], p);
        }
    }
    __syncthreads();
    if (t < BM)
        partial[(((size_t)b * SS) + s0 + t) * (size_t)tiles_y + blockIdx.y] = s_red[t];
}

// ---------------- K2-fallback (round-2 fused-convert kernel) --------------
#define FBK 32
#define FLDK (FBK + 8)
__global__ __launch_bounds__(256, 2)
void gemm_scores_fallback(const float* __restrict__ keys,
                          const float* __restrict__ W2,
                          const float* __restrict__ w1q,
                          const float* __restrict__ v,
                          float* __restrict__ partial) {
    __shared__ bf16 a_lds[BM][FLDK];
    __shared__ bf16 b_lds[BN][FLDK];
    __shared__ float s_red[BM];

    const int t    = threadIdx.x;
    const int lane = t & 63;
    const int w    = t >> 6;
    const int ml   = lane & 15;
    const int kg   = lane >> 4;
    const int b    = blockIdx.z;
    const int s0   = blockIdx.x * BM;
    const int a0   = blockIdx.y * BN;
    const int m_off = (w & 1) * 64;
    const int n_off = (w >> 1) * 64;

    const float* Ablk = keys + ((size_t)b * SS + s0) * DD;
    const float* Bblk = W2 + (size_t)a0 * DD;

    if (t < BM) s_red[t] = 0.f;

    floatx4 acc[4][4];
#pragma unroll
    for (int mi = 0; mi < 4; ++mi)
#pragma unroll
        for (int ni = 0; ni < 4; ++ni)
            acc[mi][ni] = (floatx4)(0.f);

    float4 ga[4], gb[4];
#pragma unroll
    for (int i = 0; i < 4; ++i) {
        int idx = t + 256 * i;
        int r = idx >> 3, c = idx & 7;
        ga[i] = *(const float4*)(Ablk + (size_t)r * DD + c * 4);
        gb[i] = *(const float4*)(Bblk + (size_t)r * DD + c * 4);
    }

    for (int chunk = 0; chunk < DD / FBK; ++chunk) {
        __syncthreads();
#pragma unroll
        for (int i = 0; i < 4; ++i) {
            int idx = t + 256 * i;
            int r = idx >> 3, c = idx & 7;
            bf16x4 pa, pb;
            pa[0] = (bf16)ga[i].x; pa[1] = (bf16)ga[i].y;
            pa[2] = (bf16)ga[i].z; pa[3] = (bf16)ga[i].w;
            pb[0] = (bf16)gb[i].x; pb[1] = (bf16)gb[i].y;
            pb[2] = (bf16)gb[i].z; pb[3] = (bf16)gb[i].w;
            *(bf16x4*)&a_lds[r][c * 4] = pa;
            *(bf16x4*)&b_lds[r][c * 4] = pb;
        }
        __syncthreads();
        if (chunk < DD / FBK - 1) {
            int d0 = (chunk + 1) * FBK;
#pragma unroll
            for (int i = 0; i < 4; ++i) {
                int idx = t + 256 * i;
                int r = idx >> 3, c = idx & 7;
                ga[i] = *(const float4*)(Ablk + (size_t)r * DD + d0 + c * 4);
                gb[i] = *(const float4*)(Bblk + (size_t)r * DD + d0 + c * 4);
            }
        }
        bf16x8 af[4], bfr[4];
#pragma unroll
        for (int mi = 0; mi < 4; ++mi)
            af[mi] = *(const bf16x8*)&a_lds[m_off + mi * 16 + ml][kg * 8];
#pragma unroll
        for (int ni = 0; ni < 4; ++ni)
            bfr[ni] = *(const bf16x8*)&b_lds[n_off + ni * 16 + ml][kg * 8];
#pragma unroll
        for (int mi = 0; mi < 4; ++mi)
#pragma unroll
            for (int ni = 0; ni < 4; ++ni)
                acc[mi][ni] = __builtin_amdgcn_mfma_f32_16x16x32_bf16(
                    af[mi], bfr[ni], acc[mi][ni], 0, 0, 0);
    }

    float w1qa[4], va[4];
#pragma unroll
    for (int ni = 0; ni < 4; ++ni) {
        int a = a0 + n_off + ni * 16 + ml;
        w1qa[ni] = w1q[(size_t)b * AD + a];
        va[ni]   = v[a];
    }
#pragma unroll
    for (int mi = 0; mi < 4; ++mi) {
#pragma unroll
        for (int reg = 0; reg < 4; ++reg) {
            float p = 0.f;
#pragma unroll
            for (int ni = 0; ni < 4; ++ni) {
                float x = acc[mi][ni][reg] + w1qa[ni];
                float th = 1.f - 2.f / (1.f + __expf(2.f * x));
                p = fmaf(th, va[ni], p);
            }
            p += __shfl_xor(p, 1);
            p += __shfl_xor(p, 2);
            p += __shfl_xor(p, 4);
            p += __shfl_xor(p, 8);
            if (ml == 0)
                atomicAdd(&s_red[m_off + mi * 16 + kg * 4 + reg], p);
        }
    }
    __syncthreads();
    if (t < BM)
        partial[(((size_t)b * SS) + s0 + t) * 4 + blockIdx.y] = s_red[t];
}

// ---------------- K3: combine partials + masked softmax over s ------------
__global__ void softmax_kernel(const float* __restrict__ partial,
                               const int* __restrict__ mask_i32,
                               const unsigned char* __restrict__ mask_u8,
                               const int* __restrict__ flag,
                               float* __restrict__ out) {
    const int b = blockIdx.x;
    const int t = threadIdx.x;
    __shared__ float rmax[4], rsum[4];
    const int wid = t >> 6, lane = t & 63;

    float sv[8]; int mv[8];
    const int bytes = (*flag != 0);
#pragma unroll
    for (int k = 0; k < 8; ++k) {
        int i = t + 256 * k;
        float4 p4 = *(const float4*)(partial + ((size_t)b * SS + i) * 4);
        sv[k] = (p4.x + p4.y) + (p4.z + p4.w);
        mv[k] = bytes ? (int)mask_u8[(size_t)b * SS + i]
                      : mask_i32[(size_t)b * SS + i];
    }

    float mx = -INFINITY;
#pragma unroll
    for (int k = 0; k < 8; ++k) mx = fmaxf(mx, mv[k] ? sv[k] : -INFINITY);
#pragma unroll
    for (int off = 32; off > 0; off >>= 1) mx = fmaxf(mx, __shfl_xor(mx, off));
    if (lane == 0) rmax[wid] = mx;
    __syncthreads();
    mx = fmaxf(fmaxf(rmax[0], rmax[1]), fmaxf(rmax[2], rmax[3]));

    float ev[8]; float sum = 0.f;
#pragma unroll
    for (int k = 0; k < 8; ++k) {
        ev[k] = mv[k] ? __expf(sv[k] - mx) : 0.f;
        sum += ev[k];
    }
#pragma unroll
    for (int off = 32; off > 0; off >>= 1) sum += __shfl_xor(sum, off);
    if (lane == 0) rsum[wid] = sum;
    __syncthreads();
    sum = (rsum[0] + rsum[1]) + (rsum[2] + rsum[3]);
    float inv = 1.f / sum;
#pragma unroll
    for (int k = 0; k < 8; ++k)
        out[(size_t)b * SS + t + 256 * k] = ev[k] * inv;
}

extern "C" void kernel_launch(void* const* d_in, const int* in_sizes, int n_in,
                              void* d_out, int out_size, void* d_ws, size_t ws_size,
                              hipStream_t stream) {
    const float* query = (const float*)d_in[0];
    const float* keys  = (const float*)d_in[1];
    const void*  mask  = d_in[2];
    const float* W1    = (const float*)d_in[3];
    const float* W2    = (const float*)d_in[4];
    const float* v     = (const float*)d_in[5];
    float* out = (float*)d_out;

    // ws layout (bytes): [flag 256][w1q 64K][partial 1M][keysb 64M][W2b 0.5M]
    char* wsb = (char*)d_ws;
    int*   flag    = (int*)wsb;
    float* w1q     = (float*)(wsb + 256);
    float* partial = (float*)(wsb + 256 + 65536);
    bf16*  keysb   = (bf16*)(wsb + 256 + 65536 + 1048576);
    bf16*  W2b     = (bf16*)(wsb + 256 + 65536 + 1048576 + (size_t)BB * SS * DD * 2);
    size_t need = 256 + 65536 + 1048576 + (size_t)BB * SS * DD * 2 + (size_t)AD * DD * 2;

    hipMemsetAsync(flag, 0, 4, stream);
    mask_probe_kernel<<<64, 256, 0, stream>>>((const unsigned char*)mask, flag);
    w1q_kernel<<<dim3(AD / 4, BB), 256, 0, stream>>>(query, W1, w1q);

    if (ws_size >= need) {
        int nk8 = BB * SS * DD / 8;   // 4,194,304
        int nw8 = AD * DD / 8;        // 32,768
        convert_kernel<<<(nk8 + 255) / 256, 256, 0, stream>>>(keys, keysb, nk8);
        convert_kernel<<<(nw8 + 255) / 256, 256, 0, stream>>>(W2, W2b, nw8);
        gemm_scores_mfma<<<dim3(SS / BM, AD / BN, BB), 256, 0, stream>>>(
            keysb, W2b, w1q, v, partial, AD / BN);
    } else {
        gemm_scores_fallback<<<dim3(SS / BM, AD / BN, BB), 256, 0, stream>>>(
            keys, W2, w1q, v, partial);
    }
    softmax_kernel<<<BB, 256, 0, stream>>>(partial, (const int*)mask,
                                           (const unsigned char*)mask, flag, out);
}